// Round 15
// baseline (348.254 us; speedup 1.0000x reference)
//
#include <hip/hip_runtime.h>

typedef unsigned short u16;
typedef unsigned int   u32;
typedef __attribute__((ext_vector_type(8))) short bf16x8;
typedef __attribute__((ext_vector_type(4))) float f32x4;
typedef __attribute__((ext_vector_type(4))) int   int4v;

#define DEV static __device__ __forceinline__

DEV u16 f2b(float f){ u32 u = __builtin_bit_cast(u32,f); u = (u + 0x7FFFu + ((u>>16)&1u))>>16; return (u16)u; }
DEV float b2f(u16 h){ return __builtin_bit_cast(float,(u32)h<<16); }
DEV float mpsilu(float t){ return t/(1.f+__expf(-t)) * 1.6778523489932886f; } // silu/0.596
DEV u32 cvtpk(float lo, float hi){ u32 r; asm("v_cvt_pk_bf16_f32 %0, %1, %2" : "=v"(r) : "v"(lo), "v"(hi)); return r; }

DEV void gload16(void* l, const void* g){
  __builtin_amdgcn_global_load_lds(
    (const __attribute__((address_space(1))) void*)g,
    (__attribute__((address_space(3))) void*)l, 16, 0, 0);
}

// ---------------- workspace layout (bytes) ----------------
#define OFF_W0B    0ull          // bf16 [9][512][512]
#define OFF_W1B    4718592ull    // bf16 [9][512][512]
#define OFF_WSKIPB 9437184ull    // bf16 [512][256]
#define OFF_WQKVB  9699328ull    // bf16 [1536][512] (rows permuted: h*192+w*64+c)
#define OFF_WPROJB 11272192ull   // bf16 [512][512]
#define OFF_CEMB   13893632ull   // f32  [16][512]
#define OFF_XSKIP  13926400ull   // bf16 [16][1024][512]   (dead after pixnorm)
#define OFF_YATT   13926400ull   //   then bf16 [16][1024][512]
#define OFF_XNORM  47480832ull   // bf16 [16][1024][512]   (kept through proj)
#define OFF_PAD0   97812480ull   // bf16 [16][34][34][512] (dead after conv0)
#define OFF_Q      97812480ull   //   then bf16 [16][8][1024][64]
#define OFF_PAD1   116752384ull  // bf16 [16][34][34][512] (dead after conv1)
#define OFF_V      116752384ull  //   then bf16 [16][8][64][1024]
#define OFF_XB     135692288ull  // bf16 [16][1024][256]
#define OFF_XRESB  169246720ull  // bf16 [16][1024][512]
#define OFF_K      186023936ull  // bf16 [16][8][1024][64]

// ------------- kernels -------------
// one merged prologue launch (all parts independent):
//   blocks 0..3583    : weight normalize/cast/relayout
//   blocks 3584..3847 : pad-halo zeroing
//   blocks 3848..5895 : cemb = emb @ normalize(w_emb)^T * gain + 1
//   blocks 5896..6151 : cast x f32 NCHW -> bf16 NHWC
__global__ __launch_bounds__(256) void k_prep(
    const float* __restrict__ w_skip, const float* __restrict__ w_res0,
    const float* __restrict__ w_res1, const float* __restrict__ w_qkv,
    const float* __restrict__ w_proj, const float* __restrict__ emb,
    const float* __restrict__ wemb,  const float* __restrict__ egain,
    const float* __restrict__ x, char* __restrict__ ws)
{
  int b = blockIdx.x, tid = threadIdx.x, lane = tid&63, wid = tid>>6;
  if(b >= 5896){
    // ---- cast x ----
    __shared__ u16 t[64*257];
    int bid = b - 5896;
    int n=bid>>4, p0=(bid&15)<<6;
    int p=tid&63, c0=tid>>6;
    u16* xb = (u16*)(ws+OFF_XB);
    for(int c=c0;c<256;c+=4)
      t[p*257+c] = f2b(x[((size_t)((n<<8)+c)<<10) + p0 + p]);
    __syncthreads();
    for(int task=tid;task<2048;task+=256){
      int pp=task>>5, oc=(task&31)<<3;
      union{u16 u[8]; int4v v;} pk;
      #pragma unroll
      for(int i=0;i<8;++i) pk.u[i]=t[pp*257+oc+i];
      *(int4v*)(xb + ((size_t)((n<<10)+p0+pp))*256 + oc) = pk.v;
    }
    return;
  }
  if(b >= 3848){
    // ---- emb modulation (w_emb norm fused) ----
    int gw = ((b-3848)*256 + tid)>>6;
    int n = gw>>9, o = gw&511;
    const float* e = emb + (size_t)n*1024;
    const float* w = wemb + (size_t)o*1024;
    float s=0, ssw=0;
    for(int i=lane*4;i<1024;i+=256){
      float4 a=*(const float4*)(e+i), bb=*(const float4*)(w+i);
      s   += a.x*bb.x + a.y*bb.y + a.z*bb.z + a.w*bb.w;
      ssw += bb.x*bb.x + bb.y*bb.y + bb.z*bb.z + bb.w*bb.w;
    }
    for(int i=1;i<64;i<<=1){ s += __shfl_xor(s,i); ssw += __shfl_xor(ssw,i); }
    if(lane==0){
      float scale = (*egain) / (1e-4f*32.0f + sqrtf(ssw));   // sqrt(1024)=32
      ((float*)(ws+OFF_CEMB))[n*512+o] = s*scale + 1.0f;
    }
    return;
  }
  if(b >= 3584){
    // ---- pad halo zero ----
    int idx = (b-3584)*256 + tid;
    int4v z = {0,0,0,0};
    for(; idx < 270336; idx += 67584){
      int chunk = idx & 63;
      int rest  = idx >> 6;
      int bp    = rest % 132;
      int rest2 = rest / 132;
      int n     = rest2 & 15;
      int buf   = rest2 >> 4;
      int py, px;
      if(bp < 34){ py=0; px=bp; }
      else if(bp < 68){ py=33; px=bp-34; }
      else if(bp < 100){ py=1+(bp-68); px=0; }
      else { py=1+(bp-100); px=33; }
      char* dst = ws + OFF_PAD0 + (size_t)buf*18939904ull
                + ((size_t)n*1156 + (size_t)py*34 + px)*1024 + (chunk<<4);
      *(int4v*)dst = z;
    }
    return;
  }
  // ---- weight normalize/cast ----
  const float* src; int fan, mode, o; u16* dstB=nullptr;
  if(b<512)       { o=b;      src=w_res0+(size_t)o*4608; fan=4608; mode=1; dstB=(u16*)(ws+OFF_W0B); }
  else if(b<1024) { o=b-512;  src=w_res1+(size_t)o*4608; fan=4608; mode=1; dstB=(u16*)(ws+OFF_W1B); }
  else if(b<1536) { o=b-1024; src=w_skip+(size_t)o*256;  fan=256;  mode=0; dstB=(u16*)(ws+OFF_WSKIPB); }
  else if(b<3072) { o=b-1536; src=w_qkv+(size_t)o*512;   fan=512;  mode=2; dstB=(u16*)(ws+OFF_WQKVB); }
  else            { o=b-3072; src=w_proj+(size_t)o*512;  fan=512;  mode=0; dstB=(u16*)(ws+OFF_WPROJB); }
  float ss=0;
  for(int i=tid;i<fan;i+=256){ float v=src[i]; ss += v*v; }
  for(int i=1;i<64;i<<=1) ss += __shfl_xor(ss,i);
  __shared__ float red[4];
  if(lane==0) red[wid]=ss;
  __syncthreads();
  ss = red[0]+red[1]+red[2]+red[3];
  float scale = 1.f / (1e-4f*sqrtf((float)fan) + sqrtf(ss));
  if(mode==1){
    // tap-major: contiguous 512-elem u16 runs per tap (coalesced writes)
    for(int t2=tid;t2<4608;t2+=256){
      int tap=t2>>9, c=t2&511;
      dstB[(size_t)tap*262144 + o*512 + c] = f2b(src[c*9+tap]*scale);
    }
  } else if(mode==2){
    // qkv: permute output row o = h*192+c*3+w  ->  h*192 + w*64 + c
    int h = o/192, rem = o - h*192, c = rem/3, w = rem - c*3;
    int onew = h*192 + w*64 + c;
    for(int i=tid;i<512;i+=256)
      dstB[(size_t)onew*512 + i] = f2b(src[i]*scale);
  } else {
    for(int i=tid;i<fan;i+=256)
      dstB[(size_t)o*fan + i] = f2b(src[i]*scale);
  }
}

// generic GEMM: C[n][p][N] = A[n][p][K] @ B[N][K]^T
// BM=256 x BN=128, BK=64, 512 thr, triple-buffer, 1 barrier/step, vmcnt(6)
// mode 1: store bf16
// mode 2: proj epilogue (mp_sum + clip -> NCHW out)
// mode 3: qkv epilogue (per-64ch-group normalize + exp2 q-prescale -> q/k/v layouts)
__global__ __launch_bounds__(512) void k_gemm(const u16* __restrict__ A, const u16* __restrict__ Bw,
    int K, int ntiles, int mode, u16* __restrict__ out_b,
    const u16* __restrict__ xresb, float* __restrict__ dout,
    u16* __restrict__ qd, u16* __restrict__ kd, u16* __restrict__ vd)
{
  __shared__ u16 SH[3*24576];   // per buf 48KB: A[256][64] @0, B[128][64] @32KB
  int bid=blockIdx.x, tid=threadIdx.x;
  int cpx = gridDim.x>>3;
  bid = (bid&7)*cpx + (bid>>3);              // XCD swizzle (grid %8==0)
  int per_n = ntiles<<2;
  int n = bid/per_n, rem = bid%per_n, mt = rem/ntiles, nt = rem%ntiles;
  int lane=tid&63, wid=tid>>6, lg=lane>>4, li=lane&15;
  int wm=(wid>>1)<<6, wn=(wid&1)<<6;
  f32x4 acc[4][4];
  f32x4 zz = {0.f,0.f,0.f,0.f};
  #pragma unroll
  for(int i=0;i<4;++i) for(int j=0;j<4;++j) acc[i][j]=zz;

  const char* apc = (const char*)(A + (size_t)(n*1024 + mt*256)*K);
  const char* bpc = (const char*)(Bw + (size_t)(nt*128)*K);
  int a_off[4], b_off[2], lofA[4], lofB[2];
  #pragma unroll
  for(int i=0;i<4;++i){
    int c = tid + (i<<9);
    int r = c>>3, sc = (c&7) ^ (r&7);
    lofA[i] = c<<4;
    a_off[i] = (r*K + sc*8)*2;
  }
  #pragma unroll
  for(int i=0;i<2;++i){
    int c = tid + (i<<9);
    int r = c>>3, sc = (c&7) ^ (r&7);
    lofB[i] = 32768 + (c<<4);
    b_off[i] = (r*K + sc*8)*2;
  }
  char* SB = (char*)SH;
  auto STAGE = [&](int step, int buf){
    int so = step<<7;    // step*128 bytes along K
    char* base = SB + buf*49152;
    #pragma unroll
    for(int i=0;i<4;++i) gload16(base + lofA[i], apc + a_off[i] + so);
    #pragma unroll
    for(int i=0;i<2;++i) gload16(base + lofB[i], bpc + b_off[i] + so);
  };
  int nsteps = K>>6;
  STAGE(0,0); STAGE(1,1);
  int bufsel = 0;
  for(int t=0;t<nsteps;++t){
    if(t < nsteps-1){ asm volatile("s_waitcnt vmcnt(6)" ::: "memory"); }
    else            { asm volatile("s_waitcnt vmcnt(0)" ::: "memory"); }
    __builtin_amdgcn_s_barrier();
    __builtin_amdgcn_sched_barrier(0);
    if(t+2 < nsteps) STAGE(t+2, (t+2)%3);
    const char* Ab = SB + bufsel*49152;
    const char* Bb = Ab + 32768;
    #pragma unroll
    for(int ks=0;ks<2;++ks){
      bf16x8 a[4], b[4];
      int bo = (lg<<4) + (ks<<6);
      #pragma unroll
      for(int i=0;i<4;++i){ int r = wm + (i<<4) + li; a[i] = *(const bf16x8*)(Ab + r*128 + (bo ^ ((r&7)<<4))); }
      #pragma unroll
      for(int j=0;j<4;++j){ int r = wn + (j<<4) + li; b[j] = *(const bf16x8*)(Bb + r*128 + (bo ^ ((r&7)<<4))); }
      __builtin_amdgcn_s_setprio(1);
      #pragma unroll
      for(int i=0;i<4;++i)
        #pragma unroll
        for(int j=0;j<4;++j)
          acc[i][j] = __builtin_amdgcn_mfma_f32_16x16x32_bf16(a[i], b[j], acc[i][j], 0, 0, 0);
      __builtin_amdgcn_s_setprio(0);
    }
    bufsel = (bufsel==2) ? 0 : bufsel+1;
  }

  if(mode==3){
    // wave's 64-oc span (nt*128+wn .. +64) == one (head, which) normalization
    // group, thanks to the weight-row permutation in k_prep.
    int g = (nt*128 + wn)>>6;          // 0..23
    int h = g/3, w = g - h*3;          // head, which(0=q,1=k,2=v)
    size_t pair = (size_t)(n*8 + h);
    #pragma unroll
    for(int mf=0;mf<4;++mf){
      #pragma unroll
      for(int jj=0;jj<4;++jj){
        float ssq = 0.f;
        #pragma unroll
        for(int nf=0;nf<4;++nf){ float t2=acc[mf][nf][jj]; ssq += t2*t2; }
        ssq += __shfl_xor(ssq,1); ssq += __shfl_xor(ssq,2);
        ssq += __shfl_xor(ssq,4); ssq += __shfl_xor(ssq,8);
        float sc = 1.f/(1e-4f + sqrtf(ssq)*0.125f);      // alpha = 1/8
        if(w==0) sc *= 0.18033688011112043f;             // 0.125*log2(e) for exp2-domain QK
        int p = mt*256 + wm + (mf<<4) + (lg<<2) + jj;
        if(w==2){
          #pragma unroll
          for(int nf=0;nf<4;++nf){
            int c=(nf<<4)+li;
            vd[pair*65536 + (size_t)c*1024 + p] = f2b(acc[mf][nf][jj]*sc);
          }
        }else{
          u16* dst = (w==0) ? qd : kd;
          #pragma unroll
          for(int nf=0;nf<4;++nf){
            int c=(nf<<4)+li;
            dst[(pair*1024 + p)*64 + c] = f2b(acc[mf][nf][jj]*sc);
          }
        }
      }
    }
    return;
  }

  int N = ntiles<<7;
  #pragma unroll
  for(int mf=0;mf<4;++mf){
    #pragma unroll
    for(int nf=0;nf<4;++nf){
      int oc = nt*128 + wn + (nf<<4) + li;
      #pragma unroll
      for(int jj=0;jj<4;++jj){
        float v = acc[mf][nf][jj];
        int p = mt*256 + wm + (mf<<4) + (lg<<2) + jj;
        size_t idx = (size_t)(n*1024+p)*N + oc;
        if(mode==1) out_b[idx]=f2b(v);
        else{
          float xr = b2f(xresb[(size_t)(n*1024+p)*512 + oc]);
          float r = (xr*0.7f + v*0.3f)*1.3130643285972254f; // / sqrt(0.58)
          r = fminf(fmaxf(r,-256.f),256.f);
          dout[((size_t)(n*512+oc)<<10) + p] = r;
        }
      }
    }
  }
}

// 3x3 conv (SAME) as implicit GEMM over padded NHWC input [n][34][34][512]
// 128x128 block tile, 4 waves (64x64), 60KB LDS -> 2 blocks/CU.
// A chunk [6][34][64ch] single-buffered per kc; B DOUBLE-buffered (2x16KB),
// staged POST-barrier (race-free). Software-pipelined A-frag register reads.
// Dynamic tap loop (full unroll blows the I-cache: FETCH +18MB, VGPR +20).
// mode 0: y = mp_silu(conv * cemb) -> pad1 ;  mode 1: x_res = mp_sum(xnorm, conv, .3)
__global__ __launch_bounds__(256) void k_conv3x3(const u16* __restrict__ inpad, const u16* __restrict__ wt,
    int mode, const float* __restrict__ cemb, const u16* __restrict__ xnormb,
    u16* __restrict__ ypad, u16* __restrict__ xresb)
{
  __shared__ char SB[61440];   // A @0 (28672), B @28672 (2x16KB)
  int bid=blockIdx.x, tid=threadIdx.x;
  bid = (bid&7)*64 + (bid>>3);               // XCD swizzle (512 blocks)
  int n=bid>>5, rem=bid&31, mt=rem>>2, nt=rem&3;
  int lane=tid&63, wid=tid>>6, lg=lane>>4, li=lane&15;
  int wm=(wid>>1)<<6, wn=(wid&1)<<6;
  int mt4 = mt<<2;
  f32x4 acc[4][4];
  f32x4 zz={0.f,0.f,0.f,0.f};
  #pragma unroll
  for(int i=0;i<4;++i)
    #pragma unroll
    for(int j=0;j<4;++j) acc[i][j]=zz;

  const char* ipc = (const char*)(inpad + (size_t)n*591872);   // 34*34*512 elems
  const char* wtc = (const char*)wt;
  int abase[4];
  #pragma unroll
  for(int i=0;i<4;++i){ int r = wm + (i<<4) + li; abase[i] = (r>>5)*34 + (r&31); }

  auto STAGE_B = [&](int tap, int kc, int buf){
    int off = tap*524288 + (kc<<7);
    char* base = SB + 28672 + buf*16384;
    #pragma unroll
    for(int i=0;i<4;++i){
      int c = tid + (i<<8);
      int r = c>>3, sc = ((c&7) ^ (r&7))<<4;
      gload16(base + (c<<4), wtc + (nt*128+r)*1024 + sc + off);
    }
  };
  auto STAGE_A = [&](int kcn){
    #pragma unroll
    for(int i=0;i<7;++i){
      int c = tid + (i<<8);              // 0..1791 (204 slots x 8 chunks + scratch)
      int slot = c>>3; if(slot>203) slot=203;
      int scol = ((c&7) ^ (slot&7))<<4;
      int py = (slot*241)>>13;
      int px = slot - py*34;
      gload16(SB + (c<<4), ipc + (size_t)((mt4+py)*34+px)*1024 + (kcn<<7) + scol);
    }
  };
  bf16x8 ar[2][4];
  auto LOAD_A = [&](int tap){
    int dy = (tap*11)>>5;
    int dd = dy*34 + (tap - dy*3);
    #pragma unroll
    for(int ks=0;ks<2;++ks){
      int bo = (lg<<4) + (ks<<6);
      #pragma unroll
      for(int i=0;i<4;++i){
        int slot = abase[i] + dd;
        ar[ks][i] = *(const bf16x8*)(SB + slot*128 + (bo ^ ((slot&7)<<4)));
      }
    }
  };

  // prologue: stage A(kc=0) and B(0,0) into buf0
  STAGE_A(0);
  STAGE_B(0,0,0);
  int bbuf = 0;
  for(int kc=0;kc<8;++kc){
    for(int tap=0;tap<9;++tap){
      // drain own loads, then rendezvous
      if(tap==8){ asm volatile("s_waitcnt vmcnt(0) lgkmcnt(0)" ::: "memory"); }
      else      { asm volatile("s_waitcnt vmcnt(0)" ::: "memory"); }
      __builtin_amdgcn_s_barrier();
      __builtin_amdgcn_sched_barrier(0);
      // post-barrier staging (race-free): target buffer's last readers were
      // at the previous step, already retired by every wave at this barrier.
      if(tap==8){
        if(kc<7){ STAGE_A(kc+1); STAGE_B(0, kc+1, bbuf^1); }
      } else {
        STAGE_B(tap+1, kc, bbuf^1);
      }
      if(tap==0) LOAD_A(0);
      const char* Bb = SB + 28672 + bbuf*16384;
      #pragma unroll
      for(int ks=0;ks<2;++ks){
        bf16x8 b[4];
        int bo = (lg<<4) + (ks<<6);
        #pragma unroll
        for(int j=0;j<4;++j){ int r = wn + (j<<4) + li; b[j] = *(const bf16x8*)(Bb + r*128 + (bo ^ ((r&7)<<4))); }
        __builtin_amdgcn_s_setprio(1);
        #pragma unroll
        for(int i=0;i<4;++i)
          #pragma unroll
          for(int j=0;j<4;++j)
            acc[i][j] = __builtin_amdgcn_mfma_f32_16x16x32_bf16(ar[ks][i], b[j], acc[i][j], 0, 0, 0);
        __builtin_amdgcn_s_setprio(0);
      }
      if(tap<8) LOAD_A(tap+1);           // prefetch next tap's A-frags (A stable in kc)
      bbuf ^= 1;
    }
  }

  #pragma unroll
  for(int mf=0;mf<4;++mf){
    #pragma unroll
    for(int nf=0;nf<4;++nf){
      int oc = nt*128 + wn + (nf<<4) + li;
      float ce = (mode==0) ? cemb[n*512+oc] : 0.f;
      #pragma unroll
      for(int jj=0;jj<4;++jj){
        float v = acc[mf][nf][jj];
        int p = mt*128 + wm + (mf<<4) + (lg<<2) + jj;
        int py=p>>5, px=p&31;
        if(mode==0){
          float s = mpsilu(v*ce);
          ypad[((size_t)n*1156 + (size_t)(py+1)*34 + (px+1))*512 + oc] = f2b(s);
        }else{
          size_t ix = (size_t)(n*1024+p)*512 + oc;
          float r = (b2f(xnormb[ix])*0.7f + v*0.3f)*1.3130643285972254f;
          xresb[ix]=f2b(r);
        }
      }
    }
  }
}

// per-pixel channel norm of x_skip(bf16) -> x_norm bf16 and mp_silu -> padded bf16
__global__ __launch_bounds__(256) void k_pixnorm(const u16* __restrict__ xs,
    u16* __restrict__ xn, u16* __restrict__ pad0)
{
  int tid=threadIdx.x, lane=tid&63, wid=tid>>6;
  for(int p = blockIdx.x*4 + wid; p < 16384; p += gridDim.x*4){
    union{u16 u[8]; int4v v;} in;
    in.v = *(const int4v*)(xs + (size_t)p*512 + lane*8);
    float f[8]; float ss=0.f;
    #pragma unroll
    for(int i=0;i<8;++i){ f[i]=b2f(in.u[i]); ss += f[i]*f[i]; }
    for(int i=1;i<64;i<<=1) ss += __shfl_xor(ss,i);
    float sc = 1.f/(1e-4f + sqrtf(ss)*0.04419417382415922f);   // alpha = 1/sqrt(512)
    union{u16 u[8]; int4v v;} on, op;
    #pragma unroll
    for(int i=0;i<8;++i){ float v=f[i]*sc; on.u[i]=f2b(v); op.u[i]=f2b(mpsilu(v)); }
    *(int4v*)(xn + (size_t)p*512 + lane*8) = on.v;
    int n=p>>10, py=(p>>5)&31, px=p&31;
    u16* pd = pad0 + ((size_t)n*1156 + (size_t)(py+1)*34 + (px+1))*512;
    *(int4v*)(pd + lane*8) = op.v;
  }
}

// flash attention, swapped-QK^T, exp2-domain softmax, defer-max, cvt_pk P-pack.
// 512 thr / 8 waves per block covering 256 q rows (4 blocks per pair, same XCD),
// gload_lds double-buffered K/V (1 barrier/k-tile, stage issued POST-barrier),
// Q hoisted to regs. LDS exactly 64KB: per-wave alpha broadcast aliased into the
// wave's own P strip (write+read strictly precede the P-pack overwrite each tile).
__global__ __launch_bounds__(512) void k_attn(const u16* __restrict__ Q, const u16* __restrict__ Kb,
    const u16* __restrict__ Vb, u16* __restrict__ yatt)
{
  __shared__ char lds[65536];   // B0: K@0,V@8192 ; B1: K@16384,V@24576 ; P/Q @32768 (8x4KB)
  int bid=blockIdx.x, tid=threadIdx.x;
  int pair = (bid&7)*16 + (bid>>5);          // 4 qt-blocks of a pair share an XCD
  int qt2 = (bid>>3)&3;
  int n=pair>>3, h=pair&7;
  const char* qb = (const char*)(Q  + ((size_t)pair*1024 + qt2*256)*64);
  const char* kb = (const char*)(Kb + (size_t)pair*1024*64);
  const char* vb = (const char*)(Vb + (size_t)pair*64*1024);
  int lane=tid&63, wid=tid>>6, lg=lane>>4, li=lane&15;
  int wq=wid<<5;
  char* Pt = lds + 32768;
  float* awave = (float*)(Pt + (wq<<7));   // 128B alpha scratch aliased in own P strip

  // per-wave Q stage (own 32 rows of the 256) into P region, hoist frags to regs
  #pragma unroll
  for(int i=0;i<4;++i){
    int c = lane + (i<<6);           // 0..255 within wave's 4KB
    int r = wq + (c>>3);
    int sc = ((c&7) ^ (r&7))<<4;
    gload16(Pt + (wq<<7) + (c<<4), qb + (size_t)r*128 + sc);
  }
  asm volatile("s_waitcnt vmcnt(0)" ::: "memory");
  bf16x8 bq[2][2];
  #pragma unroll
  for(int qq=0;qq<2;++qq)
    #pragma unroll
    for(int ks=0;ks<2;++ks){
      int r=wq+(qq<<4)+li; int bo=(lg<<4)+(ks<<6);
      bq[qq][ks]=*(const bf16x8*)(Pt + r*128 + (bo ^ ((r&7)<<4)));
    }
  asm volatile("s_waitcnt lgkmcnt(0)" ::: "memory");
  __builtin_amdgcn_sched_barrier(0);

  auto STAGE = [&](int kt, int buf){
    char* kd = lds + buf*16384;
    { int c = tid; int r = c>>3; int sc = ((c&7) ^ (r&7))<<4;
      gload16(kd + (c<<4), kb + (size_t)kt*8192 + (r<<7) + sc); }
    { int c = tid; int r = c>>3; int sc = ((c&7) ^ (r&7))<<4;
      gload16(kd + 8192 + (c<<4), vb + (size_t)r*2048 + kt*128 + sc); }
  };
  STAGE(0,0);

  f32x4 o0[2][4];
  float m0=-1e30f, m1=-1e30f, l0=0.f, l1=0.f;
  f32x4 zz={0.f,0.f,0.f,0.f};
  #pragma unroll
  for(int i=0;i<2;++i) for(int j=0;j<4;++j) o0[i][j]=zz;

  for(int kt=0;kt<16;++kt){
    asm volatile("s_waitcnt vmcnt(0)" ::: "memory");
    __builtin_amdgcn_s_barrier();
    __builtin_amdgcn_sched_barrier(0);
    if(kt<15) STAGE(kt+1, (kt+1)&1);
    const char* Kt = lds + (kt&1)*16384;
    const char* Vt = Kt + 8192;
    // S^T = mfma(K, Q): lane owns P[q=wq+qq*16+li][k=kk*16+lg*4+jj]
    f32x4 s[4][2];
    #pragma unroll
    for(int i=0;i<4;++i){ s[i][0]=zz; s[i][1]=zz; }
    #pragma unroll
    for(int ks=0;ks<2;++ks){
      int bo=(lg<<4)+(ks<<6);
      bf16x8 a[4];
      #pragma unroll
      for(int kk=0;kk<4;++kk){ int r=(kk<<4)+li; a[kk]=*(const bf16x8*)(Kt + r*128 + (bo ^ ((r&7)<<4))); }
      __builtin_amdgcn_s_setprio(1);
      #pragma unroll
      for(int kk=0;kk<4;++kk)
        #pragma unroll
        for(int qq=0;qq<2;++qq)
          s[kk][qq] = __builtin_amdgcn_mfma_f32_16x16x32_bf16(a[kk], bq[qq][ks], s[kk][qq], 0,0,0);
      __builtin_amdgcn_s_setprio(0);
    }
    float pm0=-1e30f, pm1=-1e30f;
    #pragma unroll
    for(int kk=0;kk<4;++kk)
      #pragma unroll
      for(int jj=0;jj<4;++jj){ pm0=fmaxf(pm0,s[kk][0][jj]); pm1=fmaxf(pm1,s[kk][1][jj]); }
    pm0=fmaxf(pm0,__shfl_xor(pm0,16)); pm0=fmaxf(pm0,__shfl_xor(pm0,32));
    pm1=fmaxf(pm1,__shfl_xor(pm1,16)); pm1=fmaxf(pm1,__shfl_xor(pm1,32));
    if(!__all((pm0 <= m0+11.5f) && (pm1 <= m1+11.5f))){
      float mn0=fmaxf(m0,pm0), mn1=fmaxf(m1,pm1);
      float al0=__builtin_amdgcn_exp2f(m0-mn0), al1=__builtin_amdgcn_exp2f(m1-mn1);
      if(lg==0){ awave[li]=al0; awave[16+li]=al1; }
      m0=mn0; m1=mn1; l0*=al0; l1*=al1;
      #pragma unroll
      for(int mf=0;mf<2;++mf)
        #pragma unroll
        for(int jj=0;jj<4;++jj){
          float am = awave[(mf<<4)+(lg<<2)+jj];
          #pragma unroll
          for(int cf=0;cf<4;++cf) o0[mf][cf][jj]*=am;
        }
    }
    float rs0=0.f, rs1=0.f;
    #pragma unroll
    for(int kk=0;kk<4;++kk)
      #pragma unroll
      for(int jj=0;jj<4;++jj){
        float p0=__builtin_amdgcn_exp2f(s[kk][0][jj]-m0); s[kk][0][jj]=p0; rs0+=p0;
        float p1=__builtin_amdgcn_exp2f(s[kk][1][jj]-m1); s[kk][1][jj]=p1; rs1+=p1;
      }
    rs0+=__shfl_xor(rs0,16); rs0+=__shfl_xor(rs0,32);
    rs1+=__shfl_xor(rs1,16); rs1+=__shfl_xor(rs1,32);
    l0+=rs0; l1+=rs1;
    // P -> LDS [own 32 q rows][64 k] bf16 (swizzled), warp-private
    #pragma unroll
    for(int qq=0;qq<2;++qq){
      int q = wq+(qq<<4)+li;
      int rsw = (q&7)<<4;
      #pragma unroll
      for(int kk=0;kk<4;++kk){
        uint2 w;
        w.x = cvtpk(s[kk][qq][0], s[kk][qq][1]);
        w.y = cvtpk(s[kk][qq][2], s[kk][qq][3]);
        int bo = ((kk<<5)+(lg<<3)) ^ rsw;
        *(uint2*)(Pt + q*128 + bo) = w;
      }
    }
    // O += P @ V^T   (per-wave LDS ops are in-order; no barrier needed)
    #pragma unroll
    for(int ks=0;ks<2;++ks){
      int bo=(lg<<4)+(ks<<6);
      bf16x8 a[2], b[4];
      #pragma unroll
      for(int i=0;i<2;++i){ int r=wq+(i<<4)+li; a[i]=*(const bf16x8*)(Pt + r*128 + (bo ^ ((r&7)<<4))); }
      #pragma unroll
      for(int j=0;j<4;++j){ int r=(j<<4)+li;    b[j]=*(const bf16x8*)(Vt + r*128 + (bo ^ ((r&7)<<4))); }
      __builtin_amdgcn_s_setprio(1);
      #pragma unroll
      for(int i=0;i<2;++i)
        #pragma unroll
        for(int j=0;j<4;++j)
          o0[i][j] = __builtin_amdgcn_mfma_f32_16x16x32_bf16(a[i], b[j], o0[i][j], 0,0,0);
      __builtin_amdgcn_s_setprio(0);
    }
  }
  // epilogue: broadcast 1/l per q via aliased per-wave scratch (P dead after last PV)
  if(lg==0){ awave[li]=1.f/l0; awave[16+li]=1.f/l1; }
  #pragma unroll
  for(int mf=0;mf<2;++mf)
    #pragma unroll
    for(int jj=0;jj<4;++jj){
      float rl = awave[(mf<<4)+(lg<<2)+jj];
      int p=(qt2<<8)+wq+(mf<<4)+(lg<<2)+jj;
      #pragma unroll
      for(int nf=0;nf<4;++nf){
        int c=(nf<<4)+li;
        yatt[((size_t)(n*1024)+p)*512 + (h<<6) + c] = f2b(o0[mf][nf][jj]*rl);
      }
    }
}

// ------------- host -------------
extern "C" void kernel_launch(void* const* d_in, const int* in_sizes, int n_in,
                              void* d_out, int out_size, void* d_ws, size_t ws_size,
                              hipStream_t stream)
{
  (void)in_sizes; (void)n_in; (void)out_size; (void)ws_size;
  const float* x      = (const float*)d_in[0];
  const float* emb    = (const float*)d_in[1];
  const float* w_skip = (const float*)d_in[2];
  const float* w_res0 = (const float*)d_in[3];
  const float* w_emb  = (const float*)d_in[4];
  const float* w_res1 = (const float*)d_in[5];
  const float* w_qkv  = (const float*)d_in[6];
  const float* w_proj = (const float*)d_in[7];
  const float* egain  = (const float*)d_in[8];
  char* ws = (char*)d_ws;
  float* dout = (float*)d_out;

  u16* w0b    = (u16*)(ws+OFF_W0B);
  u16* w1b    = (u16*)(ws+OFF_W1B);
  u16* wskipb = (u16*)(ws+OFF_WSKIPB);
  u16* wqkvb  = (u16*)(ws+OFF_WQKVB);
  u16* wprojb = (u16*)(ws+OFF_WPROJB);
  float* cemb = (float*)(ws+OFF_CEMB);
  u16* xskipb = (u16*)(ws+OFF_XSKIP);
  u16* yatt   = (u16*)(ws+OFF_YATT);
  u16* xnormb = (u16*)(ws+OFF_XNORM);
  u16* pad0   = (u16*)(ws+OFF_PAD0);
  u16* qbuf   = (u16*)(ws+OFF_Q);
  u16* pad1   = (u16*)(ws+OFF_PAD1);
  u16* vbuf   = (u16*)(ws+OFF_V);
  u16* xb     = (u16*)(ws+OFF_XB);
  u16* xresb  = (u16*)(ws+OFF_XRESB);
  u16* kbuf   = (u16*)(ws+OFF_K);

  // merged prologue: weights + halo zero + emb modulation + x cast
  hipLaunchKernelGGL(k_prep, dim3(6152), dim3(256), 0, stream,
                     w_skip, w_res0, w_res1, w_qkv, w_proj, emb, w_emb, egain, x, ws);
  // skip conv 1x1 (K=256, N=512) -> bf16
  hipLaunchKernelGGL(k_gemm, dim3(256), dim3(512), 0, stream,
                     xb, wskipb, 256, 4, 1, xskipb, (const u16*)nullptr, (float*)nullptr,
                     (u16*)nullptr, (u16*)nullptr, (u16*)nullptr);
  hipLaunchKernelGGL(k_pixnorm, dim3(1024), dim3(256), 0, stream, xskipb, xnormb, pad0);
  // res0 3x3 + emb-mod + silu
  hipLaunchKernelGGL(k_conv3x3, dim3(512), dim3(256), 0, stream,
                     pad0, w0b, 0, cemb, (const u16*)nullptr, pad1, (u16*)nullptr);
  // res1 3x3 + mp_sum residual
  hipLaunchKernelGGL(k_conv3x3, dim3(512), dim3(256), 0, stream,
                     pad1, w1b, 1, (const float*)nullptr, xnormb, (u16*)nullptr, xresb);
  // qkv 1x1 (K=512, N=1536) + fused per-head-group normalize -> q/k/v layouts
  hipLaunchKernelGGL(k_gemm, dim3(768), dim3(512), 0, stream,
                     xresb, wqkvb, 512, 12, 3, (u16*)nullptr, (const u16*)nullptr, (float*)nullptr,
                     qbuf, kbuf, vbuf);
  hipLaunchKernelGGL(k_attn, dim3(512), dim3(512), 0, stream, qbuf, kbuf, vbuf, yatt);
  // proj 1x1 + mp_sum + clip -> NCHW out
  hipLaunchKernelGGL(k_gemm, dim3(256), dim3(512), 0, stream,
                     yatt, wprojb, 512, 4, 2, (u16*)nullptr, xresb, dout,
                     (u16*)nullptr, (u16*)nullptr, (u16*)nullptr);
}

// Round 16
// 336.218 us; speedup vs baseline: 1.0358x; 1.0358x over previous
//
#include <hip/hip_runtime.h>

typedef unsigned short u16;
typedef unsigned int   u32;
typedef __attribute__((ext_vector_type(8))) short bf16x8;
typedef __attribute__((ext_vector_type(4))) float f32x4;
typedef __attribute__((ext_vector_type(4))) int   int4v;

#define DEV static __device__ __forceinline__

DEV u16 f2b(float f){ u32 u = __builtin_bit_cast(u32,f); u = (u + 0x7FFFu + ((u>>16)&1u))>>16; return (u16)u; }
DEV float b2f(u16 h){ return __builtin_bit_cast(float,(u32)h<<16); }
DEV float mpsilu(float t){ return t/(1.f+__expf(-t)) * 1.6778523489932886f; } // silu/0.596
DEV u32 cvtpk(float lo, float hi){ u32 r; asm("v_cvt_pk_bf16_f32 %0, %1, %2" : "=v"(r) : "v"(lo), "v"(hi)); return r; }

DEV void gload16(void* l, const void* g){
  __builtin_amdgcn_global_load_lds(
    (const __attribute__((address_space(1))) void*)g,
    (__attribute__((address_space(3))) void*)l, 16, 0, 0);
}

// ---------------- workspace layout (bytes) ----------------
#define OFF_W0B    0ull          // bf16 [9][512][512]
#define OFF_W1B    4718592ull    // bf16 [9][512][512]
#define OFF_WSKIPB 9437184ull    // bf16 [512][256]
#define OFF_WQKVB  9699328ull    // bf16 [1536][512] (rows permuted: h*192+w*64+c)
#define OFF_WPROJB 11272192ull   // bf16 [512][512]
#define OFF_CEMB   13893632ull   // f32  [16][512]
#define OFF_XSKIP  13926400ull   // bf16 [16][1024][512]   (dead after pixnorm)
#define OFF_YATT   13926400ull   //   then bf16 [16][1024][512]
#define OFF_XNORM  47480832ull   // bf16 [16][1024][512]   (kept through proj)
#define OFF_PAD0   97812480ull   // bf16 [16][34][34][512] (dead after conv0)
#define OFF_Q      97812480ull   //   then bf16 [16][8][1024][64]
#define OFF_PAD1   116752384ull  // bf16 [16][34][34][512] (dead after conv1)
#define OFF_V      116752384ull  //   then bf16 [16][8][64][1024]
#define OFF_XB     135692288ull  // bf16 [16][1024][256]
#define OFF_XRESB  169246720ull  // bf16 [16][1024][512]
#define OFF_K      186023936ull  // bf16 [16][8][1024][64]

// ------------- kernels -------------
// one merged prologue launch (all parts independent):
//   blocks 0..3583    : weight normalize/cast/relayout
//   blocks 3584..3847 : pad-halo zeroing
//   blocks 3848..5895 : cemb = emb @ normalize(w_emb)^T * gain + 1
//   blocks 5896..6151 : cast x f32 NCHW -> bf16 NHWC
__global__ __launch_bounds__(256) void k_prep(
    const float* __restrict__ w_skip, const float* __restrict__ w_res0,
    const float* __restrict__ w_res1, const float* __restrict__ w_qkv,
    const float* __restrict__ w_proj, const float* __restrict__ emb,
    const float* __restrict__ wemb,  const float* __restrict__ egain,
    const float* __restrict__ x, char* __restrict__ ws)
{
  int b = blockIdx.x, tid = threadIdx.x, lane = tid&63, wid = tid>>6;
  if(b >= 5896){
    // ---- cast x ----
    __shared__ u16 t[64*257];
    int bid = b - 5896;
    int n=bid>>4, p0=(bid&15)<<6;
    int p=tid&63, c0=tid>>6;
    u16* xb = (u16*)(ws+OFF_XB);
    for(int c=c0;c<256;c+=4)
      t[p*257+c] = f2b(x[((size_t)((n<<8)+c)<<10) + p0 + p]);
    __syncthreads();
    for(int task=tid;task<2048;task+=256){
      int pp=task>>5, oc=(task&31)<<3;
      union{u16 u[8]; int4v v;} pk;
      #pragma unroll
      for(int i=0;i<8;++i) pk.u[i]=t[pp*257+oc+i];
      *(int4v*)(xb + ((size_t)((n<<10)+p0+pp))*256 + oc) = pk.v;
    }
    return;
  }
  if(b >= 3848){
    // ---- emb modulation (w_emb norm fused) ----
    int gw = ((b-3848)*256 + tid)>>6;
    int n = gw>>9, o = gw&511;
    const float* e = emb + (size_t)n*1024;
    const float* w = wemb + (size_t)o*1024;
    float s=0, ssw=0;
    for(int i=lane*4;i<1024;i+=256){
      float4 a=*(const float4*)(e+i), bb=*(const float4*)(w+i);
      s   += a.x*bb.x + a.y*bb.y + a.z*bb.z + a.w*bb.w;
      ssw += bb.x*bb.x + bb.y*bb.y + bb.z*bb.z + bb.w*bb.w;
    }
    for(int i=1;i<64;i<<=1){ s += __shfl_xor(s,i); ssw += __shfl_xor(ssw,i); }
    if(lane==0){
      float scale = (*egain) / (1e-4f*32.0f + sqrtf(ssw));   // sqrt(1024)=32
      ((float*)(ws+OFF_CEMB))[n*512+o] = s*scale + 1.0f;
    }
    return;
  }
  if(b >= 3584){
    // ---- pad halo zero ----
    int idx = (b-3584)*256 + tid;
    int4v z = {0,0,0,0};
    for(; idx < 270336; idx += 67584){
      int chunk = idx & 63;
      int rest  = idx >> 6;
      int bp    = rest % 132;
      int rest2 = rest / 132;
      int n     = rest2 & 15;
      int buf   = rest2 >> 4;
      int py, px;
      if(bp < 34){ py=0; px=bp; }
      else if(bp < 68){ py=33; px=bp-34; }
      else if(bp < 100){ py=1+(bp-68); px=0; }
      else { py=1+(bp-100); px=33; }
      char* dst = ws + OFF_PAD0 + (size_t)buf*18939904ull
                + ((size_t)n*1156 + (size_t)py*34 + px)*1024 + (chunk<<4);
      *(int4v*)dst = z;
    }
    return;
  }
  // ---- weight normalize/cast ----
  const float* src; int fan, mode, o; u16* dstB=nullptr;
  if(b<512)       { o=b;      src=w_res0+(size_t)o*4608; fan=4608; mode=1; dstB=(u16*)(ws+OFF_W0B); }
  else if(b<1024) { o=b-512;  src=w_res1+(size_t)o*4608; fan=4608; mode=1; dstB=(u16*)(ws+OFF_W1B); }
  else if(b<1536) { o=b-1024; src=w_skip+(size_t)o*256;  fan=256;  mode=0; dstB=(u16*)(ws+OFF_WSKIPB); }
  else if(b<3072) { o=b-1536; src=w_qkv+(size_t)o*512;   fan=512;  mode=2; dstB=(u16*)(ws+OFF_WQKVB); }
  else            { o=b-3072; src=w_proj+(size_t)o*512;  fan=512;  mode=0; dstB=(u16*)(ws+OFF_WPROJB); }
  float ss=0;
  for(int i=tid;i<fan;i+=256){ float v=src[i]; ss += v*v; }
  for(int i=1;i<64;i<<=1) ss += __shfl_xor(ss,i);
  __shared__ float red[4];
  if(lane==0) red[wid]=ss;
  __syncthreads();
  ss = red[0]+red[1]+red[2]+red[3];
  float scale = 1.f / (1e-4f*sqrtf((float)fan) + sqrtf(ss));
  if(mode==1){
    // tap-major: contiguous 512-elem u16 runs per tap (coalesced writes)
    for(int t2=tid;t2<4608;t2+=256){
      int tap=t2>>9, c=t2&511;
      dstB[(size_t)tap*262144 + o*512 + c] = f2b(src[c*9+tap]*scale);
    }
  } else if(mode==2){
    // qkv: permute output row o = h*192+c*3+w  ->  h*192 + w*64 + c
    int h = o/192, rem = o - h*192, c = rem/3, w = rem - c*3;
    int onew = h*192 + w*64 + c;
    for(int i=tid;i<512;i+=256)
      dstB[(size_t)onew*512 + i] = f2b(src[i]*scale);
  } else {
    for(int i=tid;i<fan;i+=256)
      dstB[(size_t)o*fan + i] = f2b(src[i]*scale);
  }
}

// generic GEMM: C[n][p][N] = A[n][p][K] @ B[N][K]^T
// BM=256 x BN=128, BK=64, 512 thr, triple-buffer, 1 barrier/step, vmcnt(6)
// mode 1: store bf16
// mode 2: proj epilogue (mp_sum + clip -> NCHW out, float4 stores)
// mode 3: qkv epilogue (per-64ch-group normalize + exp2 q-prescale -> q/k/v layouts)
__global__ __launch_bounds__(512) void k_gemm(const u16* __restrict__ A, const u16* __restrict__ Bw,
    int K, int ntiles, int mode, u16* __restrict__ out_b,
    const u16* __restrict__ xresb, float* __restrict__ dout,
    u16* __restrict__ qd, u16* __restrict__ kd, u16* __restrict__ vd)
{
  __shared__ u16 SH[3*24576];   // per buf 48KB: A[256][64] @0, B[128][64] @32KB
  int bid=blockIdx.x, tid=threadIdx.x;
  int cpx = gridDim.x>>3;
  bid = (bid&7)*cpx + (bid>>3);              // XCD swizzle (grid %8==0)
  int per_n = ntiles<<2;
  int n = bid/per_n, rem = bid%per_n, mt = rem/ntiles, nt = rem%ntiles;
  int lane=tid&63, wid=tid>>6, lg=lane>>4, li=lane&15;
  int wm=(wid>>1)<<6, wn=(wid&1)<<6;
  f32x4 acc[4][4];
  f32x4 zz = {0.f,0.f,0.f,0.f};
  #pragma unroll
  for(int i=0;i<4;++i) for(int j=0;j<4;++j) acc[i][j]=zz;

  const char* apc = (const char*)(A + (size_t)(n*1024 + mt*256)*K);
  const char* bpc = (const char*)(Bw + (size_t)(nt*128)*K);
  int a_off[4], b_off[2], lofA[4], lofB[2];
  #pragma unroll
  for(int i=0;i<4;++i){
    int c = tid + (i<<9);
    int r = c>>3, sc = (c&7) ^ (r&7);
    lofA[i] = c<<4;
    a_off[i] = (r*K + sc*8)*2;
  }
  #pragma unroll
  for(int i=0;i<2;++i){
    int c = tid + (i<<9);
    int r = c>>3, sc = (c&7) ^ (r&7);
    lofB[i] = 32768 + (c<<4);
    b_off[i] = (r*K + sc*8)*2;
  }
  char* SB = (char*)SH;
  auto STAGE = [&](int step, int buf){
    int so = step<<7;    // step*128 bytes along K
    char* base = SB + buf*49152;
    #pragma unroll
    for(int i=0;i<4;++i) gload16(base + lofA[i], apc + a_off[i] + so);
    #pragma unroll
    for(int i=0;i<2;++i) gload16(base + lofB[i], bpc + b_off[i] + so);
  };
  int nsteps = K>>6;
  STAGE(0,0); STAGE(1,1);
  int bufsel = 0;
  for(int t=0;t<nsteps;++t){
    if(t < nsteps-1){ asm volatile("s_waitcnt vmcnt(6)" ::: "memory"); }
    else            { asm volatile("s_waitcnt vmcnt(0)" ::: "memory"); }
    __builtin_amdgcn_s_barrier();
    __builtin_amdgcn_sched_barrier(0);
    if(t+2 < nsteps) STAGE(t+2, (t+2)%3);
    const char* Ab = SB + bufsel*49152;
    const char* Bb = Ab + 32768;
    #pragma unroll
    for(int ks=0;ks<2;++ks){
      bf16x8 a[4], b[4];
      int bo = (lg<<4) + (ks<<6);
      #pragma unroll
      for(int i=0;i<4;++i){ int r = wm + (i<<4) + li; a[i] = *(const bf16x8*)(Ab + r*128 + (bo ^ ((r&7)<<4))); }
      #pragma unroll
      for(int j=0;j<4;++j){ int r = wn + (j<<4) + li; b[j] = *(const bf16x8*)(Bb + r*128 + (bo ^ ((r&7)<<4))); }
      __builtin_amdgcn_s_setprio(1);
      #pragma unroll
      for(int i=0;i<4;++i)
        #pragma unroll
        for(int j=0;j<4;++j)
          acc[i][j] = __builtin_amdgcn_mfma_f32_16x16x32_bf16(a[i], b[j], acc[i][j], 0, 0, 0);
      __builtin_amdgcn_s_setprio(0);
    }
    bufsel = (bufsel==2) ? 0 : bufsel+1;
  }

  if(mode==3){
    // wave's 64-oc span (nt*128+wn .. +64) == one (head, which) normalization
    // group, thanks to the weight-row permutation in k_prep.
    int g = (nt*128 + wn)>>6;          // 0..23
    int h = g/3, w = g - h*3;          // head, which(0=q,1=k,2=v)
    size_t pair = (size_t)(n*8 + h);
    #pragma unroll
    for(int mf=0;mf<4;++mf){
      #pragma unroll
      for(int jj=0;jj<4;++jj){
        float ssq = 0.f;
        #pragma unroll
        for(int nf=0;nf<4;++nf){ float t2=acc[mf][nf][jj]; ssq += t2*t2; }
        ssq += __shfl_xor(ssq,1); ssq += __shfl_xor(ssq,2);
        ssq += __shfl_xor(ssq,4); ssq += __shfl_xor(ssq,8);
        float sc = 1.f/(1e-4f + sqrtf(ssq)*0.125f);      // alpha = 1/8
        if(w==0) sc *= 0.18033688011112043f;             // 0.125*log2(e) for exp2-domain QK
        int p = mt*256 + wm + (mf<<4) + (lg<<2) + jj;
        if(w==2){
          #pragma unroll
          for(int nf=0;nf<4;++nf){
            int c=(nf<<4)+li;
            vd[pair*65536 + (size_t)c*1024 + p] = f2b(acc[mf][nf][jj]*sc);
          }
        }else{
          u16* dst = (w==0) ? qd : kd;
          #pragma unroll
          for(int nf=0;nf<4;++nf){
            int c=(nf<<4)+li;
            dst[(pair*1024 + p)*64 + c] = f2b(acc[mf][nf][jj]*sc);
          }
        }
      }
    }
    return;
  }

  int N = ntiles<<7;
  if(mode==2){
    // proj epilogue: 4 consecutive p per (mf,nf) -> one float4 store
    #pragma unroll
    for(int mf=0;mf<4;++mf){
      int p0 = mt*256 + wm + (mf<<4) + (lg<<2);
      #pragma unroll
      for(int nf=0;nf<4;++nf){
        int oc = nt*128 + wn + (nf<<4) + li;
        float4 r4;
        float* rp = (float*)&r4;
        #pragma unroll
        for(int jj=0;jj<4;++jj){
          float xr = b2f(xresb[(size_t)(n*1024+p0+jj)*512 + oc]);
          float r = (xr*0.7f + acc[mf][nf][jj]*0.3f)*1.3130643285972254f; // / sqrt(0.58)
          rp[jj] = fminf(fmaxf(r,-256.f),256.f);
        }
        *(float4*)(dout + ((size_t)(n*512+oc)<<10) + p0) = r4;
      }
    }
    return;
  }
  #pragma unroll
  for(int mf=0;mf<4;++mf){
    #pragma unroll
    for(int nf=0;nf<4;++nf){
      int oc = nt*128 + wn + (nf<<4) + li;
      #pragma unroll
      for(int jj=0;jj<4;++jj){
        int p = mt*256 + wm + (mf<<4) + (lg<<2) + jj;
        out_b[(size_t)(n*1024+p)*N + oc] = f2b(acc[mf][nf][jj]);
      }
    }
  }
}

// 3x3 conv (SAME) as implicit GEMM over padded NHWC input [n][34][34][512]
// 128x128 block tile, 4 waves (64x64), 60KB LDS -> 2 blocks/CU.
// A chunk [6][34][64ch] single-buffered per kc; B DOUBLE-buffered (2x16KB),
// staged POST-barrier (race-free). Software-pipelined A-frag register reads.
// Dynamic tap loop (full unroll blows the I-cache: FETCH +18MB, VGPR +20).
// mode 0: y = mp_silu(conv * cemb) -> pad1 ;  mode 1: x_res = mp_sum(xnorm, conv, .3)
__global__ __launch_bounds__(256) void k_conv3x3(const u16* __restrict__ inpad, const u16* __restrict__ wt,
    int mode, const float* __restrict__ cemb, const u16* __restrict__ xnormb,
    u16* __restrict__ ypad, u16* __restrict__ xresb)
{
  __shared__ char SB[61440];   // A @0 (28672), B @28672 (2x16KB)
  int bid=blockIdx.x, tid=threadIdx.x;
  bid = (bid&7)*64 + (bid>>3);               // XCD swizzle (512 blocks)
  int n=bid>>5, rem=bid&31, mt=rem>>2, nt=rem&3;
  int lane=tid&63, wid=tid>>6, lg=lane>>4, li=lane&15;
  int wm=(wid>>1)<<6, wn=(wid&1)<<6;
  int mt4 = mt<<2;
  f32x4 acc[4][4];
  f32x4 zz={0.f,0.f,0.f,0.f};
  #pragma unroll
  for(int i=0;i<4;++i)
    #pragma unroll
    for(int j=0;j<4;++j) acc[i][j]=zz;

  const char* ipc = (const char*)(inpad + (size_t)n*591872);   // 34*34*512 elems
  const char* wtc = (const char*)wt;
  int abase[4];
  #pragma unroll
  for(int i=0;i<4;++i){ int r = wm + (i<<4) + li; abase[i] = (r>>5)*34 + (r&31); }

  auto STAGE_B = [&](int tap, int kc, int buf){
    int off = tap*524288 + (kc<<7);
    char* base = SB + 28672 + buf*16384;
    #pragma unroll
    for(int i=0;i<4;++i){
      int c = tid + (i<<8);
      int r = c>>3, sc = ((c&7) ^ (r&7))<<4;
      gload16(base + (c<<4), wtc + (nt*128+r)*1024 + sc + off);
    }
  };
  auto STAGE_A = [&](int kcn){
    #pragma unroll
    for(int i=0;i<7;++i){
      int c = tid + (i<<8);              // 0..1791 (204 slots x 8 chunks + scratch)
      int slot = c>>3; if(slot>203) slot=203;
      int scol = ((c&7) ^ (slot&7))<<4;
      int py = (slot*241)>>13;
      int px = slot - py*34;
      gload16(SB + (c<<4), ipc + (size_t)((mt4+py)*34+px)*1024 + (kcn<<7) + scol);
    }
  };
  bf16x8 ar[2][4];
  auto LOAD_A = [&](int tap){
    int dy = (tap*11)>>5;
    int dd = dy*34 + (tap - dy*3);
    #pragma unroll
    for(int ks=0;ks<2;++ks){
      int bo = (lg<<4) + (ks<<6);
      #pragma unroll
      for(int i=0;i<4;++i){
        int slot = abase[i] + dd;
        ar[ks][i] = *(const bf16x8*)(SB + slot*128 + (bo ^ ((slot&7)<<4)));
      }
    }
  };

  // prologue: stage A(kc=0) and B(0,0) into buf0
  STAGE_A(0);
  STAGE_B(0,0,0);
  int bbuf = 0;
  for(int kc=0;kc<8;++kc){
    for(int tap=0;tap<9;++tap){
      // drain own loads, then rendezvous
      if(tap==8){ asm volatile("s_waitcnt vmcnt(0) lgkmcnt(0)" ::: "memory"); }
      else      { asm volatile("s_waitcnt vmcnt(0)" ::: "memory"); }
      __builtin_amdgcn_s_barrier();
      __builtin_amdgcn_sched_barrier(0);
      // post-barrier staging (race-free): target buffer's last readers were
      // at the previous step, already retired by every wave at this barrier.
      if(tap==8){
        if(kc<7){ STAGE_A(kc+1); STAGE_B(0, kc+1, bbuf^1); }
      } else {
        STAGE_B(tap+1, kc, bbuf^1);
      }
      if(tap==0) LOAD_A(0);
      const char* Bb = SB + 28672 + bbuf*16384;
      #pragma unroll
      for(int ks=0;ks<2;++ks){
        bf16x8 b[4];
        int bo = (lg<<4) + (ks<<6);
        #pragma unroll
        for(int j=0;j<4;++j){ int r = wn + (j<<4) + li; b[j] = *(const bf16x8*)(Bb + r*128 + (bo ^ ((r&7)<<4))); }
        __builtin_amdgcn_s_setprio(1);
        #pragma unroll
        for(int i=0;i<4;++i)
          #pragma unroll
          for(int j=0;j<4;++j)
            acc[i][j] = __builtin_amdgcn_mfma_f32_16x16x32_bf16(ar[ks][i], b[j], acc[i][j], 0, 0, 0);
        __builtin_amdgcn_s_setprio(0);
      }
      if(tap<8) LOAD_A(tap+1);           // prefetch next tap's A-frags (A stable in kc)
      bbuf ^= 1;
    }
  }

  #pragma unroll
  for(int mf=0;mf<4;++mf){
    #pragma unroll
    for(int nf=0;nf<4;++nf){
      int oc = nt*128 + wn + (nf<<4) + li;
      float ce = (mode==0) ? cemb[n*512+oc] : 0.f;
      #pragma unroll
      for(int jj=0;jj<4;++jj){
        float v = acc[mf][nf][jj];
        int p = mt*128 + wm + (mf<<4) + (lg<<2) + jj;
        int py=p>>5, px=p&31;
        if(mode==0){
          float s = mpsilu(v*ce);
          ypad[((size_t)n*1156 + (size_t)(py+1)*34 + (px+1))*512 + oc] = f2b(s);
        }else{
          size_t ix = (size_t)(n*1024+p)*512 + oc;
          float r = (b2f(xnormb[ix])*0.7f + v*0.3f)*1.3130643285972254f;
          xresb[ix]=f2b(r);
        }
      }
    }
  }
}

// per-pixel channel norm of x_skip(bf16) -> x_norm bf16 and mp_silu -> padded bf16
__global__ __launch_bounds__(256) void k_pixnorm(const u16* __restrict__ xs,
    u16* __restrict__ xn, u16* __restrict__ pad0)
{
  int tid=threadIdx.x, lane=tid&63, wid=tid>>6;
  for(int p = blockIdx.x*4 + wid; p < 16384; p += gridDim.x*4){
    union{u16 u[8]; int4v v;} in;
    in.v = *(const int4v*)(xs + (size_t)p*512 + lane*8);
    float f[8]; float ss=0.f;
    #pragma unroll
    for(int i=0;i<8;++i){ f[i]=b2f(in.u[i]); ss += f[i]*f[i]; }
    for(int i=1;i<64;i<<=1) ss += __shfl_xor(ss,i);
    float sc = 1.f/(1e-4f + sqrtf(ss)*0.04419417382415922f);   // alpha = 1/sqrt(512)
    union{u16 u[8]; int4v v;} on, op;
    #pragma unroll
    for(int i=0;i<8;++i){ float v=f[i]*sc; on.u[i]=f2b(v); op.u[i]=f2b(mpsilu(v)); }
    *(int4v*)(xn + (size_t)p*512 + lane*8) = on.v;
    int n=p>>10, py=(p>>5)&31, px=p&31;
    u16* pd = pad0 + ((size_t)n*1156 + (size_t)(py+1)*34 + (px+1))*512;
    *(int4v*)(pd + lane*8) = op.v;
  }
}

// flash attention, swapped-QK^T, exp2-domain softmax, defer-max, cvt_pk P-pack.
// 512 thr / 8 waves per block covering 256 q rows (4 blocks per pair, same XCD),
// gload_lds double-buffered K/V (1 barrier/k-tile, stage issued POST-barrier),
// Q hoisted to regs. LDS exactly 64KB: per-wave alpha broadcast aliased into the
// wave's own P strip (write+read strictly precede the P-pack overwrite each tile).
__global__ __launch_bounds__(512) void k_attn(const u16* __restrict__ Q, const u16* __restrict__ Kb,
    const u16* __restrict__ Vb, u16* __restrict__ yatt)
{
  __shared__ char lds[65536];   // B0: K@0,V@8192 ; B1: K@16384,V@24576 ; P/Q @32768 (8x4KB)
  int bid=blockIdx.x, tid=threadIdx.x;
  int pair = (bid&7)*16 + (bid>>5);          // 4 qt-blocks of a pair share an XCD
  int qt2 = (bid>>3)&3;
  int n=pair>>3, h=pair&7;
  const char* qb = (const char*)(Q  + ((size_t)pair*1024 + qt2*256)*64);
  const char* kb = (const char*)(Kb + (size_t)pair*1024*64);
  const char* vb = (const char*)(Vb + (size_t)pair*64*1024);
  int lane=tid&63, wid=tid>>6, lg=lane>>4, li=lane&15;
  int wq=wid<<5;
  char* Pt = lds + 32768;
  float* awave = (float*)(Pt + (wq<<7));   // 128B alpha scratch aliased in own P strip

  // per-wave Q stage (own 32 rows of the 256) into P region, hoist frags to regs
  #pragma unroll
  for(int i=0;i<4;++i){
    int c = lane + (i<<6);           // 0..255 within wave's 4KB
    int r = wq + (c>>3);
    int sc = ((c&7) ^ (r&7))<<4;
    gload16(Pt + (wq<<7) + (c<<4), qb + (size_t)r*128 + sc);
  }
  asm volatile("s_waitcnt vmcnt(0)" ::: "memory");
  bf16x8 bq[2][2];
  #pragma unroll
  for(int qq=0;qq<2;++qq)
    #pragma unroll
    for(int ks=0;ks<2;++ks){
      int r=wq+(qq<<4)+li; int bo=(lg<<4)+(ks<<6);
      bq[qq][ks]=*(const bf16x8*)(Pt + r*128 + (bo ^ ((r&7)<<4)));
    }
  asm volatile("s_waitcnt lgkmcnt(0)" ::: "memory");
  __builtin_amdgcn_sched_barrier(0);

  auto STAGE = [&](int kt, int buf){
    char* kd = lds + buf*16384;
    { int c = tid; int r = c>>3; int sc = ((c&7) ^ (r&7))<<4;
      gload16(kd + (c<<4), kb + (size_t)kt*8192 + (r<<7) + sc); }
    { int c = tid; int r = c>>3; int sc = ((c&7) ^ (r&7))<<4;
      gload16(kd + 8192 + (c<<4), vb + (size_t)r*2048 + kt*128 + sc); }
  };
  STAGE(0,0);

  f32x4 o0[2][4];
  float m0=-1e30f, m1=-1e30f, l0=0.f, l1=0.f;
  f32x4 zz={0.f,0.f,0.f,0.f};
  #pragma unroll
  for(int i=0;i<2;++i) for(int j=0;j<4;++j) o0[i][j]=zz;

  for(int kt=0;kt<16;++kt){
    asm volatile("s_waitcnt vmcnt(0)" ::: "memory");
    __builtin_amdgcn_s_barrier();
    __builtin_amdgcn_sched_barrier(0);
    if(kt<15) STAGE(kt+1, (kt+1)&1);
    const char* Kt = lds + (kt&1)*16384;
    const char* Vt = Kt + 8192;
    // S^T = mfma(K, Q): lane owns P[q=wq+qq*16+li][k=kk*16+lg*4+jj]
    f32x4 s[4][2];
    #pragma unroll
    for(int i=0;i<4;++i){ s[i][0]=zz; s[i][1]=zz; }
    #pragma unroll
    for(int ks=0;ks<2;++ks){
      int bo=(lg<<4)+(ks<<6);
      bf16x8 a[4];
      #pragma unroll
      for(int kk=0;kk<4;++kk){ int r=(kk<<4)+li; a[kk]=*(const bf16x8*)(Kt + r*128 + (bo ^ ((r&7)<<4))); }
      __builtin_amdgcn_s_setprio(1);
      #pragma unroll
      for(int kk=0;kk<4;++kk)
        #pragma unroll
        for(int qq=0;qq<2;++qq)
          s[kk][qq] = __builtin_amdgcn_mfma_f32_16x16x32_bf16(a[kk], bq[qq][ks], s[kk][qq], 0,0,0);
      __builtin_amdgcn_s_setprio(0);
    }
    float pm0=-1e30f, pm1=-1e30f;
    #pragma unroll
    for(int kk=0;kk<4;++kk)
      #pragma unroll
      for(int jj=0;jj<4;++jj){ pm0=fmaxf(pm0,s[kk][0][jj]); pm1=fmaxf(pm1,s[kk][1][jj]); }
    pm0=fmaxf(pm0,__shfl_xor(pm0,16)); pm0=fmaxf(pm0,__shfl_xor(pm0,32));
    pm1=fmaxf(pm1,__shfl_xor(pm1,16)); pm1=fmaxf(pm1,__shfl_xor(pm1,32));
    if(!__all((pm0 <= m0+11.5f) && (pm1 <= m1+11.5f))){
      float mn0=fmaxf(m0,pm0), mn1=fmaxf(m1,pm1);
      float al0=__builtin_amdgcn_exp2f(m0-mn0), al1=__builtin_amdgcn_exp2f(m1-mn1);
      if(lg==0){ awave[li]=al0; awave[16+li]=al1; }
      m0=mn0; m1=mn1; l0*=al0; l1*=al1;
      #pragma unroll
      for(int mf=0;mf<2;++mf)
        #pragma unroll
        for(int jj=0;jj<4;++jj){
          float am = awave[(mf<<4)+(lg<<2)+jj];
          #pragma unroll
          for(int cf=0;cf<4;++cf) o0[mf][cf][jj]*=am;
        }
    }
    float rs0=0.f, rs1=0.f;
    #pragma unroll
    for(int kk=0;kk<4;++kk)
      #pragma unroll
      for(int jj=0;jj<4;++jj){
        float p0=__builtin_amdgcn_exp2f(s[kk][0][jj]-m0); s[kk][0][jj]=p0; rs0+=p0;
        float p1=__builtin_amdgcn_exp2f(s[kk][1][jj]-m1); s[kk][1][jj]=p1; rs1+=p1;
      }
    rs0+=__shfl_xor(rs0,16); rs0+=__shfl_xor(rs0,32);
    rs1+=__shfl_xor(rs1,16); rs1+=__shfl_xor(rs1,32);
    l0+=rs0; l1+=rs1;
    // P -> LDS [own 32 q rows][64 k] bf16 (swizzled), warp-private
    #pragma unroll
    for(int qq=0;qq<2;++qq){
      int q = wq+(qq<<4)+li;
      int rsw = (q&7)<<4;
      #pragma unroll
      for(int kk=0;kk<4;++kk){
        uint2 w;
        w.x = cvtpk(s[kk][qq][0], s[kk][qq][1]);
        w.y = cvtpk(s[kk][qq][2], s[kk][qq][3]);
        int bo = ((kk<<5)+(lg<<3)) ^ rsw;
        *(uint2*)(Pt + q*128 + bo) = w;
      }
    }
    // O += P @ V^T   (per-wave LDS ops are in-order; no barrier needed)
    #pragma unroll
    for(int ks=0;ks<2;++ks){
      int bo=(lg<<4)+(ks<<6);
      bf16x8 a[2], b[4];
      #pragma unroll
      for(int i=0;i<2;++i){ int r=wq+(i<<4)+li; a[i]=*(const bf16x8*)(Pt + r*128 + (bo ^ ((r&7)<<4))); }
      #pragma unroll
      for(int j=0;j<4;++j){ int r=(j<<4)+li;    b[j]=*(const bf16x8*)(Vt + r*128 + (bo ^ ((r&7)<<4))); }
      __builtin_amdgcn_s_setprio(1);
      #pragma unroll
      for(int i=0;i<2;++i)
        #pragma unroll
        for(int j=0;j<4;++j)
          o0[i][j] = __builtin_amdgcn_mfma_f32_16x16x32_bf16(a[i], b[j], o0[i][j], 0,0,0);
      __builtin_amdgcn_s_setprio(0);
    }
  }
  // epilogue: broadcast 1/l per q via aliased per-wave scratch (P dead after last PV)
  if(lg==0){ awave[li]=1.f/l0; awave[16+li]=1.f/l1; }
  #pragma unroll
  for(int mf=0;mf<2;++mf)
    #pragma unroll
    for(int jj=0;jj<4;++jj){
      float rl = awave[(mf<<4)+(lg<<2)+jj];
      int p=(qt2<<8)+wq+(mf<<4)+(lg<<2)+jj;
      #pragma unroll
      for(int nf=0;nf<4;++nf){
        int c=(nf<<4)+li;
        yatt[((size_t)(n*1024)+p)*512 + (h<<6) + c] = f2b(o0[mf][nf][jj]*rl);
      }
    }
}

// ------------- host -------------
extern "C" void kernel_launch(void* const* d_in, const int* in_sizes, int n_in,
                              void* d_out, int out_size, void* d_ws, size_t ws_size,
                              hipStream_t stream)
{
  (void)in_sizes; (void)n_in; (void)out_size; (void)ws_size;
  const float* x      = (const float*)d_in[0];
  const float* emb    = (const float*)d_in[1];
  const float* w_skip = (const float*)d_in[2];
  const float* w_res0 = (const float*)d_in[3];
  const float* w_emb  = (const float*)d_in[4];
  const float* w_res1 = (const float*)d_in[5];
  const float* w_qkv  = (const float*)d_in[6];
  const float* w_proj = (const float*)d_in[7];
  const float* egain  = (const float*)d_in[8];
  char* ws = (char*)d_ws;
  float* dout = (float*)d_out;

  u16* w0b    = (u16*)(ws+OFF_W0B);
  u16* w1b    = (u16*)(ws+OFF_W1B);
  u16* wskipb = (u16*)(ws+OFF_WSKIPB);
  u16* wqkvb  = (u16*)(ws+OFF_WQKVB);
  u16* wprojb = (u16*)(ws+OFF_WPROJB);
  float* cemb = (float*)(ws+OFF_CEMB);
  u16* xskipb = (u16*)(ws+OFF_XSKIP);
  u16* yatt   = (u16*)(ws+OFF_YATT);
  u16* xnormb = (u16*)(ws+OFF_XNORM);
  u16* pad0   = (u16*)(ws+OFF_PAD0);
  u16* qbuf   = (u16*)(ws+OFF_Q);
  u16* pad1   = (u16*)(ws+OFF_PAD1);
  u16* vbuf   = (u16*)(ws+OFF_V);
  u16* xb     = (u16*)(ws+OFF_XB);
  u16* xresb  = (u16*)(ws+OFF_XRESB);
  u16* kbuf   = (u16*)(ws+OFF_K);

  // merged prologue: weights + halo zero + emb modulation + x cast
  hipLaunchKernelGGL(k_prep, dim3(6152), dim3(256), 0, stream,
                     w_skip, w_res0, w_res1, w_qkv, w_proj, emb, w_emb, egain, x, ws);
  // skip conv 1x1 (K=256, N=512) -> bf16
  hipLaunchKernelGGL(k_gemm, dim3(256), dim3(512), 0, stream,
                     xb, wskipb, 256, 4, 1, xskipb, (const u16*)nullptr, (float*)nullptr,
                     (u16*)nullptr, (u16*)nullptr, (u16*)nullptr);
  hipLaunchKernelGGL(k_pixnorm, dim3(2048), dim3(256), 0, stream, xskipb, xnormb, pad0);
  // res0 3x3 + emb-mod + silu
  hipLaunchKernelGGL(k_conv3x3, dim3(512), dim3(256), 0, stream,
                     pad0, w0b, 0, cemb, (const u16*)nullptr, pad1, (u16*)nullptr);
  // res1 3x3 + mp_sum residual
  hipLaunchKernelGGL(k_conv3x3, dim3(512), dim3(256), 0, stream,
                     pad1, w1b, 1, (const float*)nullptr, xnormb, (u16*)nullptr, xresb);
  // qkv 1x1 (K=512, N=1536) + fused per-head-group normalize -> q/k/v layouts
  hipLaunchKernelGGL(k_gemm, dim3(768), dim3(512), 0, stream,
                     xresb, wqkvb, 512, 12, 3, (u16*)nullptr, (const u16*)nullptr, (float*)nullptr,
                     qbuf, kbuf, vbuf);
  hipLaunchKernelGGL(k_attn, dim3(512), dim3(512), 0, stream, qbuf, kbuf, vbuf, yatt);
  // proj 1x1 + mp_sum + clip -> NCHW out
  hipLaunchKernelGGL(k_gemm, dim3(256), dim3(512), 0, stream,
                     yatt, wprojb, 512, 4, 2, (u16*)nullptr, xresb, dout,
                     (u16*)nullptr, (u16*)nullptr, (u16*)nullptr);
}